// Round 13
// baseline (540.785 us; speedup 1.0000x reference)
//
#include <hip/hip_runtime.h>
#include <hip/hip_bf16.h>
#include <math.h>

// Problem dims
#define B_SZ 32
#define S_SZ 512
#define C_SZ 512
#define E_SZ 256
#define H_SZ 8
#define D_SZ 32
#define L_SZ 4
#define N_TOK (B_SZ * S_SZ)   // 16384
#define HID 768               // 3*E
#define MB (1048576)

typedef __attribute__((ext_vector_type(8))) short bf16x8;
typedef __attribute__((ext_vector_type(4))) float f32x4_t;

__device__ __forceinline__ float gelu_f(float x) {
    return 0.5f * x * (1.0f + erff(x * 0.70710678118654752f));
}

__device__ __forceinline__ ushort f2bf(float f) {
    uint u = __float_as_uint(f);
    return (ushort)((u + 0x7FFFu + ((u >> 16) & 1u)) >> 16);
}
// RTNE pair-convert; lowers to v_cvt_pk_bf16_f32 on gfx950
__device__ __forceinline__ uint pack2(float a, float b) {
    __hip_bfloat162 h = __float22bfloat162_rn(make_float2(a, b));
    union { __hip_bfloat162 h; uint u; } c; c.h = h;
    return c.u;
}
__device__ __forceinline__ void unpack8(uint4 u, float* f) {
    f[0] = __uint_as_float((u.x & 0xFFFFu) << 16); f[1] = __uint_as_float(u.x & 0xFFFF0000u);
    f[2] = __uint_as_float((u.y & 0xFFFFu) << 16); f[3] = __uint_as_float(u.y & 0xFFFF0000u);
    f[4] = __uint_as_float((u.z & 0xFFFFu) << 16); f[5] = __uint_as_float(u.z & 0xFFFF0000u);
    f[6] = __uint_as_float((u.w & 0xFFFFu) << 16); f[7] = __uint_as_float(u.w & 0xFFFF0000u);
}

// async global->LDS, 16B per lane; LDS dest = wave-uniform base + lane*16
__device__ __forceinline__ void gload16(const ushort* g, ushort* l) {
    __builtin_amdgcn_global_load_lds(
        (const __attribute__((address_space(1))) void*)g,
        (__attribute__((address_space(3))) void*)l, 16, 0, 0);
}

// ---------------------------------------------------------------------------
// ONE setup kernel: cnn fp32->bf16 (blocks 0..4095), all-weights cvt
// (4096..5631), qkv bias concat (5632..5643).
// ---------------------------------------------------------------------------
__global__ __launch_bounds__(256)
void setup_kernel(const float* __restrict__ cnn, const float* __restrict__ cnn_w,
                  const float* __restrict__ Wo, const float* __restrict__ Wq,
                  const float* __restrict__ Wk, const float* __restrict__ Wv,
                  const float* __restrict__ mw1, const float* __restrict__ mw2,
                  const float* __restrict__ ow1, const float* __restrict__ ow2,
                  const float* __restrict__ bq, const float* __restrict__ bk,
                  const float* __restrict__ bv, ushort* __restrict__ cnnb,
                  ushort* __restrict__ wb, float* __restrict__ bqkv)
{
    const int bid = blockIdx.x, tid = threadIdx.x;
    if (bid < 4096) {
        const int i = (bid * 256 + tid) * 8;
        const float4 a = *(const float4*)(cnn + i);
        const float4 b = *(const float4*)(cnn + i + 4);
        uint4 o;
        o.x = pack2(a.x, a.y); o.y = pack2(a.z, a.w);
        o.z = pack2(b.x, b.y); o.w = pack2(b.z, b.w);
        *(uint4*)(cnnb + i) = o;
    } else if (bid < 5632) {
        const int i = ((bid - 4096) * 256 + tid) * 8;
        const float* src;
        if (i < 131072)       src = cnn_w + i;
        else if (i < 393216)  src = Wo + (i - 131072);
        else if (i < 1179648) {
            const int r = i - 393216;
            const int layer = r / 196608, rem = r % 196608;
            const int sub = rem >> 16, off = rem & 65535;
            src = (sub == 0 ? Wq : sub == 1 ? Wk : Wv) + layer * 65536 + off;
        }
        else if (i < 1966080) src = mw1 + (i - 1179648);
        else if (i < 2752512) src = mw2 + (i - 1966080);
        else if (i < 2883584) src = ow1 + (i - 2752512);
        else                  src = ow2 + (i - 2883584);
        const float4 a = *(const float4*)src;
        const float4 b = *(const float4*)(src + 4);
        uint4 o;
        o.x = pack2(a.x, a.y); o.y = pack2(a.z, a.w);
        o.z = pack2(b.x, b.y); o.w = pack2(b.z, b.w);
        *(uint4*)(wb + i) = o;
    } else {
        const int idx = (bid - 5632) * 256 + tid;   // 0..3071
        const int layer = idx / 768, j = idx % 768;
        float v = (j < 256) ? bq[layer * 256 + j]
                : (j < 512) ? bk[layer * 256 + j - 256]
                            : bv[layer * 256 + j - 512];
        bqkv[layer * 768 + j] = v;
    }
}

// ---------------------------------------------------------------------------
// bf16 MFMA GEMM, tile 128x64, BK=64, 4 waves (2x2), counted-vmcnt dbuf,
// source/read XOR swizzle, LDS-bounce coalesced bf16 epilogue.
// EPI=1: fused QKV split (q|k -> Cb [N][512], v -> Cb2 [b][h][32][512]).
// ---------------------------------------------------------------------------
template<int ACT, int EPI, bool OF, bool OB>
__global__ __launch_bounds__(256)
void gemm_bt2_kernel(const ushort* __restrict__ A, const ushort* __restrict__ W,
                     const float* __restrict__ bias, const float* __restrict__ bias2,
                     float* __restrict__ Cf, ushort* __restrict__ Cb,
                     ushort* __restrict__ Cb2, int M, int K, int F)
{
    __shared__ __align__(16) ushort As[2][128 * 64];   // 32KB
    __shared__ __align__(16) ushort Bs[2][64 * 64];    // 16KB
    ushort* BOUNCE = &As[0][0];
    const int tid = threadIdx.x;
    const int bm = blockIdx.x * 128, bn = blockIdx.y * 64;
    const int lane = tid & 63, w = tid >> 6;
    const int lr8 = lane >> 3, lseg = lane & 7;
    const int lsx = lseg ^ lr8;
    const int wm = w >> 1, wn = w & 1;
    const int fr = lane & 15, fk = lane >> 4;
    const int fx = fr & 7;
    f32x4_t acc[4][2] = {};

    const ushort* Ag = A + (size_t)(bm + w * 32 + lr8) * K + lsx * 8;
    const ushort* Wg = W + (size_t)(bn + w * 16 + lr8) * K + lsx * 8;

    #pragma unroll
    for (int q = 0; q < 4; ++q) gload16(Ag + (size_t)q * 8 * K, &As[0][(w * 32 + q * 8) * 64]);
    #pragma unroll
    for (int q = 0; q < 2; ++q) gload16(Wg + (size_t)q * 8 * K, &Bs[0][(w * 16 + q * 8) * 64]);

    const int NT = K >> 6;
    int cur = 0;
    for (int t = 0; t < NT; ++t) {
        if (t + 1 < NT) {
            const size_t k0 = (size_t)(t + 1) << 6;
            #pragma unroll
            for (int q = 0; q < 4; ++q)
                gload16(Ag + (size_t)q * 8 * K + k0, &As[cur ^ 1][(w * 32 + q * 8) * 64]);
            #pragma unroll
            for (int q = 0; q < 2; ++q)
                gload16(Wg + (size_t)q * 8 * K + k0, &Bs[cur ^ 1][(w * 16 + q * 8) * 64]);
            asm volatile("s_waitcnt vmcnt(6)" ::: "memory");
        } else {
            asm volatile("s_waitcnt vmcnt(0)" ::: "memory");
        }
        __builtin_amdgcn_s_barrier();
        asm volatile("" ::: "memory");
        bf16x8 af[2][4], bw[2][2];
        #pragma unroll
        for (int kk = 0; kk < 2; ++kk) {
            const int rs = ((kk * 4 + fk) ^ fx) * 8;
            #pragma unroll
            for (int i = 0; i < 4; ++i)
                af[kk][i] = *(const bf16x8*)&As[cur][(wm * 64 + i * 16 + fr) * 64 + rs];
            #pragma unroll
            for (int j = 0; j < 2; ++j)
                bw[kk][j] = *(const bf16x8*)&Bs[cur][(wn * 32 + j * 16 + fr) * 64 + rs];
        }
        #pragma unroll
        for (int kk = 0; kk < 2; ++kk)
            #pragma unroll
            for (int i = 0; i < 4; ++i)
                #pragma unroll
                for (int j = 0; j < 2; ++j)
                    acc[i][j] = __builtin_amdgcn_mfma_f32_16x16x32_bf16(af[kk][i], bw[kk][j], acc[i][j], 0, 0, 0);
        asm volatile("" ::: "memory");
        __builtin_amdgcn_s_barrier();
        cur ^= 1;
    }

    if (EPI == 1) {
        const bool vblk = (bn >= 512);
        #pragma unroll
        for (int j = 0; j < 2; ++j) {
            const int col = wn * 32 + j * 16 + fr;
            const float bb = bias[bn + col];
            #pragma unroll
            for (int i = 0; i < 4; ++i)
                #pragma unroll
                for (int r = 0; r < 4; ++r) {
                    const int row = wm * 64 + i * 16 + fk * 4 + r;
                    const ushort v = f2bf(acc[i][j][r] + bb);
                    if (vblk) BOUNCE[col * 136 + row] = v;
                    else      BOUNCE[row * 72 + col] = v;
                }
        }
        __syncthreads();
        if (vblk) {
            const int b2 = bm >> 9, r0 = bm & 511;
            #pragma unroll
            for (int it = 0; it < 4; ++it) {
                const int idx = tid + it * 256;
                const int d = idx >> 4, sc = idx & 15;
                const uint4 v = *(const uint4*)&BOUNCE[d * 136 + sc * 8];
                const int dd = bn - 512 + d;
                *(uint4*)&Cb2[((size_t)((b2 << 3) + (dd >> 5)) << 14)
                              + ((dd & 31) << 9) + r0 + sc * 8] = v;
            }
        } else {
            #pragma unroll
            for (int it = 0; it < 4; ++it) {
                const int idx = tid + it * 256;
                const int row = idx >> 3, ch = idx & 7;
                const uint4 v = *(const uint4*)&BOUNCE[row * 72 + ch * 8];
                *(uint4*)&Cb[(size_t)(bm + row) * 512 + bn + ch * 8] = v;
            }
        }
    } else {
        #pragma unroll
        for (int j = 0; j < 2; ++j) {
            const int col = bn + wn * 32 + j * 16 + fr;
            float bb = bias[col];
            if (bias2) bb += bias2[col];
            #pragma unroll
            for (int i = 0; i < 4; ++i)
                #pragma unroll
                for (int r = 0; r < 4; ++r) {
                    const int row = bm + wm * 64 + i * 16 + fk * 4 + r;
                    float t = acc[i][j][r] + bb;
                    if (ACT == 1) t = gelu_f(t);
                    if (ACT == 2) t = fmaxf(t, 0.0f);
                    if (OF) Cf[(size_t)row * F + col] = t;
                    if (OB) BOUNCE[(row - bm) * 72 + (col - bn)] = f2bf(t);
                }
        }
        if (OB) {
            __syncthreads();
            #pragma unroll
            for (int it = 0; it < 4; ++it) {
                const int idx = tid + it * 256;
                const int row = idx >> 3, ch = idx & 7;
                const uint4 v = *(const uint4*)&BOUNCE[row * 72 + ch * 8];
                *(uint4*)&Cb[(size_t)(bm + row) * F + bn + ch * 8] = v;
            }
        }
    }
}

// ---------------------------------------------------------------------------
// FUSED: x_new = LN(x + A@W^T + bias) (+FINAL: x_new = LN_f(x_new), skip x wr)
// then   OUT2 = act2(x_new_bf16 @ W2^T + bias2)   [K2 = 256 always]
// STAGE2: 1 = MLP1 (F2=768, gelu, row-major out stride 768)
//         2 = QKV  (F2=768, none; cols<512 -> out2a [N][512]; cols>=512 ->
//                   out2b = vt [b][h][32][512] transposed)
//         3 = HEAD1(F2=512, gelu, row-major out stride 512)
// Tile BM=64 x BN=256, 512 threads = 8 waves, grid M/64, 1 block/CU.
// x_new staged in LDS xS[64][264] (pad, reuses Bs); W2 streamed in 64x256
// chunks (dbuf, counted vmcnt, src XOR swizzle); bounce (reuses As).
// ---------------------------------------------------------------------------
template<bool FINAL, int STAGE2, int F2>
__global__ __launch_bounds__(512)
void gemm_ln_fused(const ushort* __restrict__ A, const ushort* __restrict__ W,
                   const float* __restrict__ bias, float* __restrict__ x,
                   const float* __restrict__ lnw, const float* __restrict__ lnb,
                   const float* __restrict__ lnfw, const float* __restrict__ lnfb,
                   const ushort* __restrict__ W2, const float* __restrict__ bias2,
                   ushort* __restrict__ out2a, ushort* __restrict__ out2b, int K)
{
    __shared__ __align__(16) ushort As[2][64 * 64];    // 16KB (later: bounce)
    __shared__ __align__(16) ushort Bs[2][256 * 64];   // 64KB (later: xS[64][264])
    __shared__ __align__(16) ushort WcS[2][64 * 256];  // 64KB stage-2 W chunks
    __shared__ float psum[64][8], psq[64][8], murs[64][2];
    const int tid = threadIdx.x;
    const int bm = blockIdx.x * 64;
    const int lane = tid & 63, w = tid >> 6;
    const int lr8 = lane >> 3, lseg = lane & 7;
    const int lsx = lseg ^ lr8;
    const int fr = lane & 15, fk = lane >> 4;
    const int fx = fr & 7;
    f32x4_t acc[4][2] = {};

    const ushort* Ag = A + (size_t)(bm + w * 8 + lr8) * K + lsx * 8;
    const ushort* Wg = W + (size_t)(w * 32 + lr8) * K + lsx * 8;

    gload16(Ag, &As[0][(w * 8) * 64]);
    #pragma unroll
    for (int q = 0; q < 4; ++q) gload16(Wg + (size_t)q * 8 * K, &Bs[0][(w * 32 + q * 8) * 64]);

    const int NT = K >> 6;
    int cur = 0;
    for (int t = 0; t < NT; ++t) {
        if (t + 1 < NT) {
            const size_t k0 = (size_t)(t + 1) << 6;
            gload16(Ag + k0, &As[cur ^ 1][(w * 8) * 64]);
            #pragma unroll
            for (int q = 0; q < 4; ++q)
                gload16(Wg + (size_t)q * 8 * K + k0, &Bs[cur ^ 1][(w * 32 + q * 8) * 64]);
            asm volatile("s_waitcnt vmcnt(5)" ::: "memory");
        } else {
            asm volatile("s_waitcnt vmcnt(0)" ::: "memory");
        }
        __builtin_amdgcn_s_barrier();
        asm volatile("" ::: "memory");
        bf16x8 af[2][4], bw[2][2];
        #pragma unroll
        for (int kk = 0; kk < 2; ++kk) {
            const int rs = ((kk * 4 + fk) ^ fx) * 8;
            #pragma unroll
            for (int i = 0; i < 4; ++i)
                af[kk][i] = *(const bf16x8*)&As[cur][(i * 16 + fr) * 64 + rs];
            #pragma unroll
            for (int j = 0; j < 2; ++j)
                bw[kk][j] = *(const bf16x8*)&Bs[cur][(w * 32 + j * 16 + fr) * 64 + rs];
        }
        #pragma unroll
        for (int kk = 0; kk < 2; ++kk)
            #pragma unroll
            for (int i = 0; i < 4; ++i)
                #pragma unroll
                for (int j = 0; j < 2; ++j)
                    acc[i][j] = __builtin_amdgcn_mfma_f32_16x16x32_bf16(af[kk][i], bw[kk][j], acc[i][j], 0, 0, 0);
        asm volatile("" ::: "memory");
        __builtin_amdgcn_s_barrier();
        cur ^= 1;
    }

    // ---- LN epilogue: y = acc + bias + x(resid) ----------------------------
    ushort* xS = &Bs[0][0];     // [64][264] — Bs dead after K-loop
    ushort* BO = &As[0][0];     // bounce [.][72] — As dead after K-loop
    float y[4][2][4];
    #pragma unroll
    for (int j = 0; j < 2; ++j) {
        const int col = w * 32 + j * 16 + fr;
        const float bb = bias[col];
        #pragma unroll
        for (int i = 0; i < 4; ++i)
            #pragma unroll
            for (int r = 0; r < 4; ++r) {
                const int row = i * 16 + fk * 4 + r;
                y[i][j][r] = acc[i][j][r] + bb + x[(size_t)(bm + row) * 256 + col];
            }
    }
    #pragma unroll
    for (int i = 0; i < 4; ++i)
        #pragma unroll
        for (int r = 0; r < 4; ++r) {
            float s = y[i][0][r] + y[i][1][r];
            float q = y[i][0][r] * y[i][0][r] + y[i][1][r] * y[i][1][r];
            #pragma unroll
            for (int off = 1; off < 16; off <<= 1) {
                s += __shfl_xor(s, off);
                q += __shfl_xor(q, off);
            }
            if (fr == 0) {
                psum[i * 16 + fk * 4 + r][w] = s;
                psq [i * 16 + fk * 4 + r][w] = q;
            }
        }
    __syncthreads();
    if (tid < 64) {
        float ms = 0.f, mq = 0.f;
        #pragma unroll
        for (int ww = 0; ww < 8; ++ww) { ms += psum[tid][ww]; mq += psq[tid][ww]; }
        const float mu = ms * (1.0f / 256.0f);
        const float var = mq * (1.0f / 256.0f) - mu * mu;
        murs[tid][0] = mu;
        murs[tid][1] = rsqrtf(var + 1e-5f);
    }
    __syncthreads();
    #pragma unroll
    for (int i = 0; i < 4; ++i)
        #pragma unroll
        for (int r = 0; r < 4; ++r) {
            const int row = i * 16 + fk * 4 + r;
            const float mu = murs[row][0], rs = murs[row][1];
            #pragma unroll
            for (int j = 0; j < 2; ++j) {
                const int col = w * 32 + j * 16 + fr;
                const float xn = (y[i][j][r] - mu) * rs * lnw[col] + lnb[col];
                y[i][j][r] = xn;
                if (!FINAL) {
                    x[(size_t)(bm + row) * 256 + col] = xn;
                    xS[row * 264 + col] = f2bf(xn);
                }
            }
        }
    if (FINAL) {
        __syncthreads();
        #pragma unroll
        for (int i = 0; i < 4; ++i)
            #pragma unroll
            for (int r = 0; r < 4; ++r) {
                float s = y[i][0][r] + y[i][1][r];
                float q = y[i][0][r] * y[i][0][r] + y[i][1][r] * y[i][1][r];
                #pragma unroll
                for (int off = 1; off < 16; off <<= 1) {
                    s += __shfl_xor(s, off);
                    q += __shfl_xor(q, off);
                }
                if (fr == 0) {
                    psum[i * 16 + fk * 4 + r][w] = s;
                    psq [i * 16 + fk * 4 + r][w] = q;
                }
            }
        __syncthreads();
        if (tid < 64) {
            float ms = 0.f, mq = 0.f;
            #pragma unroll
            for (int ww = 0; ww < 8; ++ww) { ms += psum[tid][ww]; mq += psq[tid][ww]; }
            const float mu = ms * (1.0f / 256.0f);
            const float var = mq * (1.0f / 256.0f) - mu * mu;
            murs[tid][0] = mu;
            murs[tid][1] = rsqrtf(var + 1e-5f);
        }
        __syncthreads();
        #pragma unroll
        for (int i = 0; i < 4; ++i)
            #pragma unroll
            for (int r = 0; r < 4; ++r) {
                const int row = i * 16 + fk * 4 + r;
                const float mu = murs[row][0], rs = murs[row][1];
                #pragma unroll
                for (int j = 0; j < 2; ++j) {
                    const int col = w * 32 + j * 16 + fr;
                    const float xn = (y[i][j][r] - mu) * rs * lnfw[col] + lnfb[col];
                    xS[row * 264 + col] = f2bf(xn);
                }
            }
    }

    // ---- stage 2: OUT2 = act2(x_new @ W2^T + bias2) -------------------------
    constexpr int NF = F2 / 64;
    constexpr int OSTRIDE = (STAGE2 == 1) ? 768 : 512;
    const int tg = w & 3, ch = w >> 2;
    const int b2 = bm >> 9, s0 = bm & 511;
    const f32x4_t zz4 = {0.f, 0.f, 0.f, 0.f};

    // stage Wc[0]
    #pragma unroll
    for (int p = 0; p < 4; ++p) {
        const int row = p * 16 + (tid >> 5);
        const int ss = (tid & 31) ^ (row & 7);
        gload16(W2 + (size_t)row * 256 + ss * 8, &WcS[0][(p * 16 + w * 2) * 256]);
    }
    __syncthreads();   // drains vmcnt: Wc[0] + x writes; lgkm: xS ready

    int cw = 0;
    #pragma unroll 1
    for (int fc = 0; fc < NF; ++fc) {
        if (fc + 1 < NF) {
            #pragma unroll
            for (int p = 0; p < 4; ++p) {
                const int row = p * 16 + (tid >> 5);
                const int ss = (tid & 31) ^ (row & 7);
                gload16(W2 + (size_t)((fc + 1) * 64 + row) * 256 + ss * 8,
                        &WcS[cw ^ 1][(p * 16 + w * 2) * 256]);
            }
            asm volatile("s_waitcnt vmcnt(4)" ::: "memory");
        } else {
            asm volatile("s_waitcnt vmcnt(0)" ::: "memory");
        }
        asm volatile("s_waitcnt lgkmcnt(0)" ::: "memory");
        __builtin_amdgcn_s_barrier();
        asm volatile("" ::: "memory");

        f32x4_t a20 = zz4, a21 = zz4;
        #pragma unroll
        for (int ks = 0; ks < 8; ++ks) {
            const bf16x8 af2 = *(const bf16x8*)&xS[(tg * 16 + fr) * 264 + ks * 32 + fk * 8];
            const int sw = ((ks * 4 + fk) ^ (fr & 7)) * 8;
            const bf16x8 b0 = *(const bf16x8*)&WcS[cw][(ch * 32 + fr) * 256 + sw];
            const bf16x8 b1 = *(const bf16x8*)&WcS[cw][(ch * 32 + 16 + fr) * 256 + sw];
            a20 = __builtin_amdgcn_mfma_f32_16x16x32_bf16(af2, b0, a20, 0, 0, 0);
            a21 = __builtin_amdgcn_mfma_f32_16x16x32_bf16(af2, b1, a21, 0, 0, 0);
        }
        #pragma unroll
        for (int j2 = 0; j2 < 2; ++j2) {
            const int col_l = ch * 32 + j2 * 16 + fr;
            const float bb2 = bias2[fc * 64 + col_l];
            #pragma unroll
            for (int r = 0; r < 4; ++r) {
                float t = (j2 ? a21[r] : a20[r]) + bb2;
                if (STAGE2 != 2) t = gelu_f(t);
                const int tok = tg * 16 + fk * 4 + r;
                if (STAGE2 == 2 && fc >= 8) BO[col_l * 72 + tok] = f2bf(t);
                else                        BO[tok * 72 + col_l] = f2bf(t);
            }
        }
        asm volatile("s_waitcnt lgkmcnt(0)" ::: "memory");
        __builtin_amdgcn_s_barrier();
        asm volatile("" ::: "memory");
        if (STAGE2 == 2 && fc >= 8) {
            const int d = fc * 64 + (tid >> 3) - 512;
            const int tk8 = (tid & 7) * 8;
            const uint4 v = *(const uint4*)&BO[(tid >> 3) * 72 + tk8];
            *(uint4*)&out2b[((size_t)((b2 << 3) + (d >> 5)) << 14)
                            + ((d & 31) << 9) + s0 + tk8] = v;
        } else {
            const int row = tid >> 3, c8 = (tid & 7) * 8;
            const uint4 v = *(const uint4*)&BO[row * 72 + c8];
            *(uint4*)&out2a[(size_t)(bm + row) * OSTRIDE + fc * 64 + c8] = v;
        }
        cw ^= 1;
    }
}

// ---------------------------------------------------------------------------
// MFMA flash attention v7 (r11 best): stage-once, 1024 threads = 16 waves.
// ---------------------------------------------------------------------------
__global__ __launch_bounds__(1024)
void attn_v7(const ushort* __restrict__ qk, const ushort* __restrict__ vt,
             ushort* __restrict__ out)
{
    __shared__ __align__(16) ushort Ks[512 * 40];
    __shared__ __align__(16) ushort Vs[32 * 520];
    const int bh = blockIdx.x;
    const int b = bh >> 3, h = bh & 7;
    const int tid = threadIdx.x;
    const int w = tid >> 6, lane = tid & 63;
    const int g = lane >> 4, c = lane & 15;

    #pragma unroll
    for (int i = 0; i < 2; ++i) {
        const int idx = tid + i * 1024;
        const int kr = idx >> 2, seg = idx & 3;
        const uint4 kv = *(const uint4*)(qk + ((size_t)b * 512 + kr) * 512
                                         + 256 + h * 32 + seg * 8);
        const int p = (((kr >> 2) & 1) << 4) | (((kr >> 3) & 3) << 2) | (kr & 3);
        const int pos = (kr & ~31) | p;
        *(uint4*)&Ks[pos * 40 + seg * 8] = kv;
        const int dr = idx >> 6, vseg = idx & 63;
        const uint4 vv = *(const uint4*)(vt + (size_t)bh * 16384 + dr * 512 + vseg * 8);
        *(uint4*)&Vs[dr * 520 + vseg * 8] = vv;
    }

    bf16x8 qf[2];
    #pragma unroll
    for (int j = 0; j < 2; ++j) {
        const size_t qrow = (size_t)b * 512 + (j * 16 + w) * 16 + c;
        const uint4 qv = *(const uint4*)(qk + qrow * 512 + h * 32 + g * 8);
        float f[8]; unpack8(qv, f);
        const float scale = 0.25506806865756986f;   // 1/sqrt(32) * log2(e)
        union { uint u[4]; bf16x8 v; } qq;
        #pragma unroll
        for (int t = 0; t < 4; ++t) qq.u[t] = pack2(f[2*t] * scale, f[2*t+1] * scale);
        qf[j] = qq.v;
    }
    __syncthreads();

    const f32x4_t zz = {0.f, 0.f, 0.f, 0.f};
    #pragma unroll
    for (int j = 0; j < 2; ++j) {
        float m = -INFINITY, l = 0.f;
        f32x4_t o0 = zz, o1 = zz;
        for (int kt = 0; kt < 4; ++kt) {
            const int kbase = kt * 128;
            f32x4_t s[8];
            __builtin_amdgcn_s_setprio(1);
            #pragma unroll
            for (int kf = 0; kf < 8; ++kf) {
                const bf16x8 kfrag = *(const bf16x8*)&Ks[(kbase + kf * 16 + c) * 40 + g * 8];
                s[kf] = __builtin_amdgcn_mfma_f32_16x16x32_bf16(kfrag, qf[j], zz, 0, 0, 0);
            }
            __builtin_amdgcn_s_setprio(0);

            float mt = s[0][0];
            #pragma unroll
            for (int kf = 0; kf < 8; ++kf)
                #pragma unroll
                for (int r = 0; r < 4; ++r) mt = fmaxf(mt, s[kf][r]);
            mt = fmaxf(mt, __shfl_xor(mt, 16));
            mt = fmaxf(mt, __shfl_xor(mt, 32));
            const float mn = fmaxf(m, mt);
            const float corr = exp2f(m - mn);
            m = mn;
            float lt = 0.f;
            #pragma unroll
            for (int kf = 0; kf < 8; ++kf)
                #pragma unroll
                for (int r = 0; r < 4; ++r) {
                    const float p = exp2f(s[kf][r] - mn);
                    s[kf][r] = p; lt += p;
                }
            lt += __shfl_xor(lt, 16);
            lt += __shfl_xor(lt, 32);
            l = l * corr + lt;
            #pragma unroll
            for (int r = 0; r < 4; ++r) { o0[r] *= corr; o1[r] *= corr; }

            #pragma unroll
            for (int t = 0; t < 4; ++t) {
                union { uint u[4]; bf16x8 v; } pf;
                pf.u[0] = pack2(s[2*t][0],   s[2*t][1]);
                pf.u[1] = pack2(s[2*t][2],   s[2*t][3]);
                pf.u[2] = pack2(s[2*t+1][0], s[2*t+1][1]);
                pf.u[3] = pack2(s[2*t+1][2], s[2*t+1][3]);
                const bf16x8 va0 = *(const bf16x8*)&Vs[c * 520 + kbase + t * 32 + g * 8];
                const bf16x8 va1 = *(const bf16x8*)&Vs[(16 + c) * 520 + kbase + t * 32 + g * 8];
                __builtin_amdgcn_s_setprio(1);
                o0 = __builtin_amdgcn_mfma_f32_16x16x32_bf16(va0, pf.v, o0, 0, 0, 0);
                o1 = __builtin_amdgcn_mfma_f32_16x16x32_bf16(va1, pf.v, o1, 0, 0, 0);
                __builtin_amdgcn_s_setprio(0);
            }
        }

        const float inv = 1.0f / l;
        const size_t obase = ((size_t)b * 512 + (j * 16 + w) * 16 + c) * 256 + h * 32;
        ushort4 w0, w1;
        w0.x = f2bf(o0[0] * inv); w0.y = f2bf(o0[1] * inv);
        w0.z = f2bf(o0[2] * inv); w0.w = f2bf(o0[3] * inv);
        w1.x = f2bf(o1[0] * inv); w1.y = f2bf(o1[1] * inv);
        w1.z = f2bf(o1[2] * inv); w1.w = f2bf(o1[3] * inv);
        *(ushort4*)(out + obase + g * 4)      = w0;
        *(ushort4*)(out + obase + 16 + g * 4) = w1;
    }
}

// ---------------------------------------------------------------------------
extern "C" void kernel_launch(void* const* d_in, const int* in_sizes, int n_in,
                              void* d_out, int out_size, void* d_ws, size_t ws_size,
                              hipStream_t stream)
{
    const float* cnn   = (const float*)d_in[0];
    const float* cnn_w = (const float*)d_in[1];
    const float* cnn_b = (const float*)d_in[2];
    const float* tok   = (const float*)d_in[3];
    const float* Wq    = (const float*)d_in[4];
    const float* bq    = (const float*)d_in[5];
    const float* Wk    = (const float*)d_in[6];
    const float* bk    = (const float*)d_in[7];
    const float* Wv    = (const float*)d_in[8];
    const float* bv    = (const float*)d_in[9];
    const float* Wo    = (const float*)d_in[10];
    const float* bo    = (const float*)d_in[11];
    const float* ln1w  = (const float*)d_in[12];
    const float* ln1b  = (const float*)d_in[13];
    const float* ln2w  = (const float*)d_in[14];
    const float* ln2b  = (const float*)d_in[15];
    const float* mw1   = (const float*)d_in[16];
    const float* mb1   = (const float*)d_in[17];
    const float* mw2   = (const float*)d_in[18];
    const float* mb2   = (const float*)d_in[19];
    const float* lnfw  = (const float*)d_in[20];
    const float* lnfb  = (const float*)d_in[21];
    const float* ow1   = (const float*)d_in[22];
    const float* ob1   = (const float*)d_in[23];
    const float* ow2   = (const float*)d_in[24];
    const float* ob2   = (const float*)d_in[25];

    const int M = N_TOK;
    char* ws = (char*)d_ws;

    // Workspace (byte offsets in MB), all producer/consumer pairs disjoint:
    // x[0,16) fp32 | xb/ab_[16,24) | qkb/cnnb[24,40) | hb_[40,64) | vt[64,72)
    // wb[72,78) | bqkv
    float*  x     = (float*)(ws + 0);
    ushort* xb    = (ushort*)(ws + 16 * MB);   // cnn out; dead after QKV0
    ushort* ab_   = (ushort*)(ws + 16 * MB);   // attn out (aliases xb)
    ushort* qkb   = (ushort*)(ws + 24 * MB);   // q|k [N][512]; layer3: head1 out
    ushort* cnnb  = (ushort*)(ws + 24 * MB);   // cnn bf16 (dead before qkb)
    ushort* hb_   = (ushort*)(ws + 40 * MB);   // mlp hidden [N][768]
    ushort* vt    = (ushort*)(ws + 64 * MB);   // V transposed [b][h][32][512]
    ushort* wb    = (ushort*)(ws + 72 * MB);

    ushort* cnn_wb = wb;                    // 131072
    ushort* Wob    = wb + 131072;           // 262144
    ushort* wqkv   = wb + 393216;           // 786432 = [L][768][256]
    ushort* mw1b   = wb + 1179648;          // 786432
    ushort* mw2b   = wb + 1966080;          // 786432
    ushort* ow1b   = wb + 2752512;          // 131072
    ushort* ow2b   = wb + 2883584;          // 262144
    float*  bqkv   = (float*)(ws + 72 * MB + 6291456);   // [L][768] fp32

    setup_kernel<<<dim3(5644), dim3(256), 0, stream>>>(
        cnn, cnn_w, Wo, Wq, Wk, Wv, mw1, mw2, ow1, ow2, bq, bk, bv,
        cnnb, wb, bqkv);

    // x = cnn @ cnn_w^T + cnn_b + tok[0]  -> x fp32 + xb bf16
    gemm_bt2_kernel<0, 0, true, true><<<dim3(M / 128, E_SZ / 64), dim3(256), 0, stream>>>(
        cnnb, cnn_wb, cnn_b, tok, x, xb, nullptr, M, C_SZ, E_SZ);

    // layer-0 QKV (standalone): q|k -> qkb, v -> vt
    gemm_bt2_kernel<0, 1, false, false><<<dim3(M / 128, HID / 64), dim3(256), 0, stream>>>(
        xb, wqkv, bqkv, nullptr, nullptr, qkb, vt, M, E_SZ, HID);

    for (int i = 0; i < L_SZ; ++i) {
        attn_v7<<<dim3(B_SZ * H_SZ), dim3(1024), 0, stream>>>(qkb, vt, ab_);

        // x = LN1(x + ab@Wo^T + bo); hb = gelu(x_new @ mw1^T + mb1)
        gemm_ln_fused<false, 1, 768><<<dim3(M / 64), dim3(512), 0, stream>>>(
            ab_, Wob + (size_t)i * 65536, bo + (size_t)i * E_SZ, x,
            ln1w + (size_t)i * E_SZ, ln1b + (size_t)i * E_SZ, nullptr, nullptr,
            mw1b + (size_t)i * HID * E_SZ, mb1 + (size_t)i * HID,
            hb_, nullptr, E_SZ);

        if (i < L_SZ - 1) {
            // x = LN2(x + hb@mw2^T + mb2); next layer's QKV fused
            gemm_ln_fused<false, 2, 768><<<dim3(M / 64), dim3(512), 0, stream>>>(
                hb_, mw2b + (size_t)i * E_SZ * HID, mb2 + (size_t)i * E_SZ, x,
                ln2w + (size_t)i * E_SZ, ln2b + (size_t)i * E_SZ, nullptr, nullptr,
                wqkv + (size_t)(i + 1) * 196608, bqkv + (size_t)(i + 1) * 768,
                qkb, vt, HID);
        } else {
            // x_new = LN_f(LN2(x + mlp2)); head1 = gelu(x_new @ ow1^T + ob1) -> qkb
            gemm_ln_fused<true, 3, 512><<<dim3(M / 64), dim3(512), 0, stream>>>(
                hb_, mw2b + (size_t)i * E_SZ * HID, mb2 + (size_t)i * E_SZ, x,
                ln2w + (size_t)i * E_SZ, ln2b + (size_t)i * E_SZ, lnfw, lnfb,
                ow1b, ob1, qkb, nullptr, HID);
        }
    }

    // out = relu(head1 @ ow2^T + ob2) -> d_out fp32
    gemm_bt2_kernel<2, 0, true, false><<<dim3(M / 128, C_SZ / 64), dim3(256), 0, stream>>>(
        qkb, ow2b, ob2, nullptr, (float*)d_out, nullptr, nullptr, M, 2 * E_SZ, C_SZ);
}

// Round 14
// 504.377 us; speedup vs baseline: 1.0722x; 1.0722x over previous
//
#include <hip/hip_runtime.h>
#include <hip/hip_bf16.h>
#include <math.h>

// Problem dims
#define B_SZ 32
#define S_SZ 512
#define C_SZ 512
#define E_SZ 256
#define H_SZ 8
#define D_SZ 32
#define L_SZ 4
#define N_TOK (B_SZ * S_SZ)   // 16384
#define HID 768               // 3*E
#define MB (1048576)

typedef __attribute__((ext_vector_type(8))) short bf16x8;
typedef __attribute__((ext_vector_type(4))) float f32x4_t;

__device__ __forceinline__ float gelu_f(float x) {
    return 0.5f * x * (1.0f + erff(x * 0.70710678118654752f));
}

__device__ __forceinline__ ushort f2bf(float f) {
    uint u = __float_as_uint(f);
    return (ushort)((u + 0x7FFFu + ((u >> 16) & 1u)) >> 16);
}
// RTNE pair-convert; lowers to v_cvt_pk_bf16_f32 on gfx950
__device__ __forceinline__ uint pack2(float a, float b) {
    __hip_bfloat162 h = __float22bfloat162_rn(make_float2(a, b));
    union { __hip_bfloat162 h; uint u; } c; c.h = h;
    return c.u;
}
__device__ __forceinline__ void unpack8(uint4 u, float* f) {
    f[0] = __uint_as_float((u.x & 0xFFFFu) << 16); f[1] = __uint_as_float(u.x & 0xFFFF0000u);
    f[2] = __uint_as_float((u.y & 0xFFFFu) << 16); f[3] = __uint_as_float(u.y & 0xFFFF0000u);
    f[4] = __uint_as_float((u.z & 0xFFFFu) << 16); f[5] = __uint_as_float(u.z & 0xFFFF0000u);
    f[6] = __uint_as_float((u.w & 0xFFFFu) << 16); f[7] = __uint_as_float(u.w & 0xFFFF0000u);
}

// async global->LDS, 16B per lane; LDS dest = wave-uniform base + lane*16
__device__ __forceinline__ void gload16(const ushort* g, ushort* l) {
    __builtin_amdgcn_global_load_lds(
        (const __attribute__((address_space(1))) void*)g,
        (__attribute__((address_space(3))) void*)l, 16, 0, 0);
}

// ---------------------------------------------------------------------------
// ONE setup kernel: cnn fp32->bf16 (blocks 0..4095), all-weights cvt
// (4096..5631), qkv bias concat (5632..5643).
// ---------------------------------------------------------------------------
__global__ __launch_bounds__(256)
void setup_kernel(const float* __restrict__ cnn, const float* __restrict__ cnn_w,
                  const float* __restrict__ Wo, const float* __restrict__ Wq,
                  const float* __restrict__ Wk, const float* __restrict__ Wv,
                  const float* __restrict__ mw1, const float* __restrict__ mw2,
                  const float* __restrict__ ow1, const float* __restrict__ ow2,
                  const float* __restrict__ bq, const float* __restrict__ bk,
                  const float* __restrict__ bv, ushort* __restrict__ cnnb,
                  ushort* __restrict__ wb, float* __restrict__ bqkv)
{
    const int bid = blockIdx.x, tid = threadIdx.x;
    if (bid < 4096) {
        const int i = (bid * 256 + tid) * 8;
        const float4 a = *(const float4*)(cnn + i);
        const float4 b = *(const float4*)(cnn + i + 4);
        uint4 o;
        o.x = pack2(a.x, a.y); o.y = pack2(a.z, a.w);
        o.z = pack2(b.x, b.y); o.w = pack2(b.z, b.w);
        *(uint4*)(cnnb + i) = o;
    } else if (bid < 5632) {
        const int i = ((bid - 4096) * 256 + tid) * 8;
        const float* src;
        if (i < 131072)       src = cnn_w + i;
        else if (i < 393216)  src = Wo + (i - 131072);
        else if (i < 1179648) {
            const int r = i - 393216;
            const int layer = r / 196608, rem = r % 196608;
            const int sub = rem >> 16, off = rem & 65535;
            src = (sub == 0 ? Wq : sub == 1 ? Wk : Wv) + layer * 65536 + off;
        }
        else if (i < 1966080) src = mw1 + (i - 1179648);
        else if (i < 2752512) src = mw2 + (i - 1966080);
        else if (i < 2883584) src = ow1 + (i - 2752512);
        else                  src = ow2 + (i - 2883584);
        const float4 a = *(const float4*)src;
        const float4 b = *(const float4*)(src + 4);
        uint4 o;
        o.x = pack2(a.x, a.y); o.y = pack2(a.z, a.w);
        o.z = pack2(b.x, b.y); o.w = pack2(b.z, b.w);
        *(uint4*)(wb + i) = o;
    } else {
        const int idx = (bid - 5632) * 256 + tid;   // 0..3071
        const int layer = idx / 768, j = idx % 768;
        float v = (j < 256) ? bq[layer * 256 + j]
                : (j < 512) ? bk[layer * 256 + j - 256]
                            : bv[layer * 256 + j - 512];
        bqkv[layer * 768 + j] = v;
    }
}

// ---------------------------------------------------------------------------
// bf16 MFMA GEMM, tile 128x64, BK=64, 4 waves (2x2), 48KB LDS -> 3 blocks/CU.
// global_load_lds staging, dbuf with COUNTED vmcnt (loads stay in flight
// across raw s_barriers). Source/read XOR swizzle. bf16 outputs bounced
// through LDS -> coalesced uint4. EPI=1: fused QKV split.
// ---------------------------------------------------------------------------
template<int ACT, int EPI, bool OF, bool OB>
__global__ __launch_bounds__(256)
void gemm_bt2_kernel(const ushort* __restrict__ A, const ushort* __restrict__ W,
                     const float* __restrict__ bias, const float* __restrict__ bias2,
                     float* __restrict__ Cf, ushort* __restrict__ Cb,
                     ushort* __restrict__ Cb2, int M, int K, int F)
{
    __shared__ __align__(16) ushort As[2][128 * 64];   // 32KB
    __shared__ __align__(16) ushort Bs[2][64 * 64];    // 16KB
    ushort* BOUNCE = &As[0][0];                        // epilogue reuse
    const int tid = threadIdx.x;
    const int bm = blockIdx.x * 128, bn = blockIdx.y * 64;
    const int lane = tid & 63, w = tid >> 6;
    const int lr8 = lane >> 3, lseg = lane & 7;
    const int lsx = lseg ^ lr8;                        // source-side swizzle
    const int wm = w >> 1, wn = w & 1;
    const int fr = lane & 15, fk = lane >> 4;
    const int fx = fr & 7;                             // read-side swizzle bits
    f32x4_t acc[4][2] = {};

    const ushort* Ag = A + (size_t)(bm + w * 32 + lr8) * K + lsx * 8;
    const ushort* Wg = W + (size_t)(bn + w * 16 + lr8) * K + lsx * 8;

    #pragma unroll
    for (int q = 0; q < 4; ++q) gload16(Ag + (size_t)q * 8 * K, &As[0][(w * 32 + q * 8) * 64]);
    #pragma unroll
    for (int q = 0; q < 2; ++q) gload16(Wg + (size_t)q * 8 * K, &Bs[0][(w * 16 + q * 8) * 64]);

    const int NT = K >> 6;
    int cur = 0;
    for (int t = 0; t < NT; ++t) {
        if (t + 1 < NT) {
            const size_t k0 = (size_t)(t + 1) << 6;
            #pragma unroll
            for (int q = 0; q < 4; ++q)
                gload16(Ag + (size_t)q * 8 * K + k0, &As[cur ^ 1][(w * 32 + q * 8) * 64]);
            #pragma unroll
            for (int q = 0; q < 2; ++q)
                gload16(Wg + (size_t)q * 8 * K + k0, &Bs[cur ^ 1][(w * 16 + q * 8) * 64]);
            asm volatile("s_waitcnt vmcnt(6)" ::: "memory");
        } else {
            asm volatile("s_waitcnt vmcnt(0)" ::: "memory");
        }
        __builtin_amdgcn_s_barrier();
        asm volatile("" ::: "memory");
        bf16x8 af[2][4], bw[2][2];
        #pragma unroll
        for (int kk = 0; kk < 2; ++kk) {
            const int rs = ((kk * 4 + fk) ^ fx) * 8;
            #pragma unroll
            for (int i = 0; i < 4; ++i)
                af[kk][i] = *(const bf16x8*)&As[cur][(wm * 64 + i * 16 + fr) * 64 + rs];
            #pragma unroll
            for (int j = 0; j < 2; ++j)
                bw[kk][j] = *(const bf16x8*)&Bs[cur][(wn * 32 + j * 16 + fr) * 64 + rs];
        }
        #pragma unroll
        for (int kk = 0; kk < 2; ++kk)
            #pragma unroll
            for (int i = 0; i < 4; ++i)
                #pragma unroll
                for (int j = 0; j < 2; ++j)
                    acc[i][j] = __builtin_amdgcn_mfma_f32_16x16x32_bf16(af[kk][i], bw[kk][j], acc[i][j], 0, 0, 0);
        asm volatile("" ::: "memory");
        __builtin_amdgcn_s_barrier();
        cur ^= 1;
    }

    // C/D layout: col = lane&15, row = (lane>>4)*4 + reg.
    if (EPI == 1) {
        const bool vblk = (bn >= 512);
        #pragma unroll
        for (int j = 0; j < 2; ++j) {
            const int col = wn * 32 + j * 16 + fr;
            const float bb = bias[bn + col];
            #pragma unroll
            for (int i = 0; i < 4; ++i)
                #pragma unroll
                for (int r = 0; r < 4; ++r) {
                    const int row = wm * 64 + i * 16 + fk * 4 + r;
                    const ushort v = f2bf(acc[i][j][r] + bb);
                    if (vblk) BOUNCE[col * 136 + row] = v;   // transposed [d][s]
                    else      BOUNCE[row * 72 + col] = v;    // [s][col]
                }
        }
        __syncthreads();
        if (vblk) {
            const int b2 = bm >> 9, r0 = bm & 511;
            #pragma unroll
            for (int it = 0; it < 4; ++it) {
                const int idx = tid + it * 256;
                const int d = idx >> 4, sc = idx & 15;
                const uint4 v = *(const uint4*)&BOUNCE[d * 136 + sc * 8];
                const int dd = bn - 512 + d;
                *(uint4*)&Cb2[((size_t)((b2 << 3) + (dd >> 5)) << 14)
                              + ((dd & 31) << 9) + r0 + sc * 8] = v;
            }
        } else {
            #pragma unroll
            for (int it = 0; it < 4; ++it) {
                const int idx = tid + it * 256;
                const int row = idx >> 3, ch = idx & 7;
                const uint4 v = *(const uint4*)&BOUNCE[row * 72 + ch * 8];
                *(uint4*)&Cb[(size_t)(bm + row) * 512 + bn + ch * 8] = v;
            }
        }
    } else {
        #pragma unroll
        for (int j = 0; j < 2; ++j) {
            const int col = bn + wn * 32 + j * 16 + fr;
            float bb = bias[col];
            if (bias2) bb += bias2[col];
            #pragma unroll
            for (int i = 0; i < 4; ++i)
                #pragma unroll
                for (int r = 0; r < 4; ++r) {
                    const int row = bm + wm * 64 + i * 16 + fk * 4 + r;
                    float t = acc[i][j][r] + bb;
                    if (ACT == 1) t = gelu_f(t);
                    if (ACT == 2) t = fmaxf(t, 0.0f);
                    if (OF) Cf[(size_t)row * F + col] = t;   // fp32: full sectors, direct
                    if (OB) BOUNCE[(row - bm) * 72 + (col - bn)] = f2bf(t);
                }
        }
        if (OB) {
            __syncthreads();
            #pragma unroll
            for (int it = 0; it < 4; ++it) {
                const int idx = tid + it * 256;
                const int row = idx >> 3, ch = idx & 7;
                const uint4 v = *(const uint4*)&BOUNCE[row * 72 + ch * 8];
                *(uint4*)&Cb[(size_t)(bm + row) * F + bn + ch * 8] = v;
            }
        }
    }
}

// ---------------------------------------------------------------------------
// Fused GEMM + residual-add + LayerNorm (F = 256 only), counted-vmcnt K-loop.
// x_new = LN(x + A@W^T + bias); writes x (fp32) and xb (bf16) in place.
// FINAL=true additionally applies the final LN in-register and skips x write.
// Tile BM=64 x BN=256, 512 threads = 8 waves. grid = M/64. K%64==0.
// ---------------------------------------------------------------------------
template<bool FINAL>
__global__ __launch_bounds__(512)
void gemm_ln_kernel(const ushort* __restrict__ A, const ushort* __restrict__ W,
                    const float* __restrict__ bias, float* __restrict__ x,
                    ushort* __restrict__ xb, const float* __restrict__ lnw,
                    const float* __restrict__ lnb, const float* __restrict__ lnfw,
                    const float* __restrict__ lnfb, int K)
{
    __shared__ __align__(16) ushort As[2][64 * 64];    // 16KB
    __shared__ __align__(16) ushort Bs[2][256 * 64];   // 64KB
    __shared__ float psum[64][8], psq[64][8], murs[64][2];
    const int tid = threadIdx.x;
    const int bm = blockIdx.x * 64;
    const int lane = tid & 63, w = tid >> 6;
    const int lr8 = lane >> 3, lseg = lane & 7;
    const int lsx = lseg ^ lr8;
    const int fr = lane & 15, fk = lane >> 4;
    const int fx = fr & 7;
    f32x4_t acc[4][2] = {};

    const ushort* Ag = A + (size_t)(bm + w * 8 + lr8) * K + lsx * 8;
    const ushort* Wg = W + (size_t)(w * 32 + lr8) * K + lsx * 8;

    gload16(Ag, &As[0][(w * 8) * 64]);
    #pragma unroll
    for (int q = 0; q < 4; ++q) gload16(Wg + (size_t)q * 8 * K, &Bs[0][(w * 32 + q * 8) * 64]);

    const int NT = K >> 6;
    int cur = 0;
    for (int t = 0; t < NT; ++t) {
        if (t + 1 < NT) {
            const size_t k0 = (size_t)(t + 1) << 6;
            gload16(Ag + k0, &As[cur ^ 1][(w * 8) * 64]);
            #pragma unroll
            for (int q = 0; q < 4; ++q)
                gload16(Wg + (size_t)q * 8 * K + k0, &Bs[cur ^ 1][(w * 32 + q * 8) * 64]);
            asm volatile("s_waitcnt vmcnt(5)" ::: "memory");
        } else {
            asm volatile("s_waitcnt vmcnt(0)" ::: "memory");
        }
        __builtin_amdgcn_s_barrier();
        asm volatile("" ::: "memory");
        bf16x8 af[2][4], bw[2][2];
        #pragma unroll
        for (int kk = 0; kk < 2; ++kk) {
            const int rs = ((kk * 4 + fk) ^ fx) * 8;
            #pragma unroll
            for (int i = 0; i < 4; ++i)
                af[kk][i] = *(const bf16x8*)&As[cur][(i * 16 + fr) * 64 + rs];
            #pragma unroll
            for (int j = 0; j < 2; ++j)
                bw[kk][j] = *(const bf16x8*)&Bs[cur][(w * 32 + j * 16 + fr) * 64 + rs];
        }
        #pragma unroll
        for (int kk = 0; kk < 2; ++kk)
            #pragma unroll
            for (int i = 0; i < 4; ++i)
                #pragma unroll
                for (int j = 0; j < 2; ++j)
                    acc[i][j] = __builtin_amdgcn_mfma_f32_16x16x32_bf16(af[kk][i], bw[kk][j], acc[i][j], 0, 0, 0);
        asm volatile("" ::: "memory");
        __builtin_amdgcn_s_barrier();
        cur ^= 1;
    }

    // ---- epilogue: y = acc + bias + x(resid), per-row LN -------------------
    float y[4][2][4];
    #pragma unroll
    for (int j = 0; j < 2; ++j) {
        const int col = w * 32 + j * 16 + fr;
        const float bb = bias[col];
        #pragma unroll
        for (int i = 0; i < 4; ++i)
            #pragma unroll
            for (int r = 0; r < 4; ++r) {
                const int row = i * 16 + fk * 4 + r;
                y[i][j][r] = acc[i][j][r] + bb + x[(size_t)(bm + row) * 256 + col];
            }
    }
    #pragma unroll
    for (int i = 0; i < 4; ++i)
        #pragma unroll
        for (int r = 0; r < 4; ++r) {
            float s = y[i][0][r] + y[i][1][r];
            float q = y[i][0][r] * y[i][0][r] + y[i][1][r] * y[i][1][r];
            #pragma unroll
            for (int off = 1; off < 16; off <<= 1) {
                s += __shfl_xor(s, off);
                q += __shfl_xor(q, off);
            }
            if (fr == 0) {
                psum[i * 16 + fk * 4 + r][w] = s;
                psq [i * 16 + fk * 4 + r][w] = q;
            }
        }
    __syncthreads();
    if (tid < 64) {
        float ms = 0.f, mq = 0.f;
        #pragma unroll
        for (int ww = 0; ww < 8; ++ww) { ms += psum[tid][ww]; mq += psq[tid][ww]; }
        const float mu = ms * (1.0f / 256.0f);
        const float var = mq * (1.0f / 256.0f) - mu * mu;
        murs[tid][0] = mu;
        murs[tid][1] = rsqrtf(var + 1e-5f);
    }
    __syncthreads();
    #pragma unroll
    for (int i = 0; i < 4; ++i)
        #pragma unroll
        for (int r = 0; r < 4; ++r) {
            const int row = i * 16 + fk * 4 + r;
            const float mu = murs[row][0], rs = murs[row][1];
            #pragma unroll
            for (int j = 0; j < 2; ++j) {
                const int col = w * 32 + j * 16 + fr;
                const float xn = (y[i][j][r] - mu) * rs * lnw[col] + lnb[col];
                y[i][j][r] = xn;
                if (!FINAL) {
                    x [(size_t)(bm + row) * 256 + col] = xn;
                    xb[(size_t)(bm + row) * 256 + col] = f2bf(xn);
                }
            }
        }
    if (FINAL) {
        __syncthreads();
        #pragma unroll
        for (int i = 0; i < 4; ++i)
            #pragma unroll
            for (int r = 0; r < 4; ++r) {
                float s = y[i][0][r] + y[i][1][r];
                float q = y[i][0][r] * y[i][0][r] + y[i][1][r] * y[i][1][r];
                #pragma unroll
                for (int off = 1; off < 16; off <<= 1) {
                    s += __shfl_xor(s, off);
                    q += __shfl_xor(q, off);
                }
                if (fr == 0) {
                    psum[i * 16 + fk * 4 + r][w] = s;
                    psq [i * 16 + fk * 4 + r][w] = q;
                }
            }
        __syncthreads();
        if (tid < 64) {
            float ms = 0.f, mq = 0.f;
            #pragma unroll
            for (int ww = 0; ww < 8; ++ww) { ms += psum[tid][ww]; mq += psq[tid][ww]; }
            const float mu = ms * (1.0f / 256.0f);
            const float var = mq * (1.0f / 256.0f) - mu * mu;
            murs[tid][0] = mu;
            murs[tid][1] = rsqrtf(var + 1e-5f);
        }
        __syncthreads();
        #pragma unroll
        for (int i = 0; i < 4; ++i)
            #pragma unroll
            for (int r = 0; r < 4; ++r) {
                const int row = i * 16 + fk * 4 + r;
                const float mu = murs[row][0], rs = murs[row][1];
                #pragma unroll
                for (int j = 0; j < 2; ++j) {
                    const int col = w * 32 + j * 16 + fr;
                    const float xn = (y[i][j][r] - mu) * rs * lnfw[col] + lnfb[col];
                    xb[(size_t)(bm + row) * 256 + col] = f2bf(xn);
                }
            }
    }
}

// ---------------------------------------------------------------------------
// MFMA flash attention v9: v7 (stage-once, 1024 threads = 16 waves) + T13
// defer-max (skip O/l rescale + corr-exp when tile max grows <= 8 in log2
// domain; wave-uniform via __all; P bounded by 2^8, fine in bf16/f32).
// ---------------------------------------------------------------------------
__global__ __launch_bounds__(1024)
void attn_v9(const ushort* __restrict__ qk, const ushort* __restrict__ vt,
             ushort* __restrict__ out)
{
    __shared__ __align__(16) ushort Ks[512 * 40];
    __shared__ __align__(16) ushort Vs[32 * 520];
    const int bh = blockIdx.x;
    const int b = bh >> 3, h = bh & 7;
    const int tid = threadIdx.x;
    const int w = tid >> 6, lane = tid & 63;
    const int g = lane >> 4, c = lane & 15;

    #pragma unroll
    for (int i = 0; i < 2; ++i) {
        const int idx = tid + i * 1024;
        const int kr = idx >> 2, seg = idx & 3;
        const uint4 kv = *(const uint4*)(qk + ((size_t)b * 512 + kr) * 512
                                         + 256 + h * 32 + seg * 8);
        const int p = (((kr >> 2) & 1) << 4) | (((kr >> 3) & 3) << 2) | (kr & 3);
        const int pos = (kr & ~31) | p;
        *(uint4*)&Ks[pos * 40 + seg * 8] = kv;
        const int dr = idx >> 6, vseg = idx & 63;
        const uint4 vv = *(const uint4*)(vt + (size_t)bh * 16384 + dr * 512 + vseg * 8);
        *(uint4*)&Vs[dr * 520 + vseg * 8] = vv;
    }

    bf16x8 qf[2];
    #pragma unroll
    for (int j = 0; j < 2; ++j) {
        const size_t qrow = (size_t)b * 512 + (j * 16 + w) * 16 + c;
        const uint4 qv = *(const uint4*)(qk + qrow * 512 + h * 32 + g * 8);
        float f[8]; unpack8(qv, f);
        const float scale = 0.25506806865756986f;   // 1/sqrt(32) * log2(e)
        union { uint u[4]; bf16x8 v; } qq;
        #pragma unroll
        for (int t = 0; t < 4; ++t) qq.u[t] = pack2(f[2*t] * scale, f[2*t+1] * scale);
        qf[j] = qq.v;
    }
    __syncthreads();

    const f32x4_t zz = {0.f, 0.f, 0.f, 0.f};
    #pragma unroll
    for (int j = 0; j < 2; ++j) {
        float m = -INFINITY, l = 0.f;
        f32x4_t o0 = zz, o1 = zz;
        for (int kt = 0; kt < 4; ++kt) {
            const int kbase = kt * 128;
            f32x4_t s[8];
            __builtin_amdgcn_s_setprio(1);
            #pragma unroll
            for (int kf = 0; kf < 8; ++kf) {
                const bf16x8 kfrag = *(const bf16x8*)&Ks[(kbase + kf * 16 + c) * 40 + g * 8];
                s[kf] = __builtin_amdgcn_mfma_f32_16x16x32_bf16(kfrag, qf[j], zz, 0, 0, 0);
            }
            __builtin_amdgcn_s_setprio(0);

            // tile max (lane holds 32 keys of its q=c; reduce over g)
            float mt = s[0][0];
            #pragma unroll
            for (int kf = 0; kf < 8; ++kf)
                #pragma unroll
                for (int r = 0; r < 4; ++r) mt = fmaxf(mt, s[kf][r]);
            mt = fmaxf(mt, __shfl_xor(mt, 16));
            mt = fmaxf(mt, __shfl_xor(mt, 32));
            // T13 defer-max: only rescale when some lane's max grew > 8 (log2)
            if (!__all(mt - m <= 8.0f)) {
                const float mn = fmaxf(m, mt);
                const float corr = exp2f(m - mn);   // exp2(-inf)=0 on 1st tile
                m = mn;
                l *= corr;
                #pragma unroll
                for (int r = 0; r < 4; ++r) { o0[r] *= corr; o1[r] *= corr; }
            }
            float lt = 0.f;
            #pragma unroll
            for (int kf = 0; kf < 8; ++kf)
                #pragma unroll
                for (int r = 0; r < 4; ++r) {
                    const float p = exp2f(s[kf][r] - m);
                    s[kf][r] = p; lt += p;
                }
            lt += __shfl_xor(lt, 16);
            lt += __shfl_xor(lt, 32);
            l += lt;

            #pragma unroll
            for (int t = 0; t < 4; ++t) {
                union { uint u[4]; bf16x8 v; } pf;
                pf.u[0] = pack2(s[2*t][0],   s[2*t][1]);
                pf.u[1] = pack2(s[2*t][2],   s[2*t][3]);
                pf.u[2] = pack2(s[2*t+1][0], s[2*t+1][1]);
                pf.u[3] = pack2(s[2*t+1][2], s[2*t+1][3]);
                const bf16x8 va0 = *(const bf16x8*)&Vs[c * 520 + kbase + t * 32 + g * 8];
                const bf16x8 va1 = *(const bf16x8*)&Vs[(16 + c) * 520 + kbase + t * 32 + g * 8];
                __builtin_amdgcn_s_setprio(1);
                o0 = __builtin_amdgcn_mfma_f32_16x16x32_bf16(va0, pf.v, o0, 0, 0, 0);
                o1 = __builtin_amdgcn_mfma_f32_16x16x32_bf16(va1, pf.v, o1, 0, 0, 0);
                __builtin_amdgcn_s_setprio(0);
            }
        }

        const float inv = 1.0f / l;
        const size_t obase = ((size_t)b * 512 + (j * 16 + w) * 16 + c) * 256 + h * 32;
        ushort4 w0, w1;
        w0.x = f2bf(o0[0] * inv); w0.y = f2bf(o0[1] * inv);
        w0.z = f2bf(o0[2] * inv); w0.w = f2bf(o0[3] * inv);
        w1.x = f2bf(o1[0] * inv); w1.y = f2bf(o1[1] * inv);
        w1.z = f2bf(o1[2] * inv); w1.w = f2bf(o1[3] * inv);
        *(ushort4*)(out + obase + g * 4)      = w0;
        *(ushort4*)(out + obase + 16 + g * 4) = w1;
    }
}

// ---------------------------------------------------------------------------
extern "C" void kernel_launch(void* const* d_in, const int* in_sizes, int n_in,
                              void* d_out, int out_size, void* d_ws, size_t ws_size,
                              hipStream_t stream)
{
    const float* cnn   = (const float*)d_in[0];
    const float* cnn_w = (const float*)d_in[1];
    const float* cnn_b = (const float*)d_in[2];
    const float* tok   = (const float*)d_in[3];
    const float* Wq    = (const float*)d_in[4];
    const float* bq    = (const float*)d_in[5];
    const float* Wk    = (const float*)d_in[6];
    const float* bk    = (const float*)d_in[7];
    const float* Wv    = (const float*)d_in[8];
    const float* bv    = (const float*)d_in[9];
    const float* Wo    = (const float*)d_in[10];
    const float* bo    = (const float*)d_in[11];
    const float* ln1w  = (const float*)d_in[12];
    const float* ln1b  = (const float*)d_in[13];
    const float* ln2w  = (const float*)d_in[14];
    const float* ln2b  = (const float*)d_in[15];
    const float* mw1   = (const float*)d_in[16];
    const float* mb1   = (const float*)d_in[17];
    const float* mw2   = (const float*)d_in[18];
    const float* mb2   = (const float*)d_in[19];
    const float* lnfw  = (const float*)d_in[20];
    const float* lnfb  = (const float*)d_in[21];
    const float* ow1   = (const float*)d_in[22];
    const float* ob1   = (const float*)d_in[23];
    const float* ow2   = (const float*)d_in[24];
    const float* ob2   = (const float*)d_in[25];

    const int M = N_TOK;
    char* ws = (char*)d_ws;

    float*  x     = (float*)(ws + 0);
    ushort* xb    = (ushort*)(ws + 16 * MB);
    ushort* qkb   = (ushort*)(ws + 24 * MB);
    ushort* cnnb  = (ushort*)(ws + 24 * MB);
    ushort* vt    = (ushort*)(ws + 40 * MB);
    ushort* ab_   = (ushort*)(ws + 48 * MB);
    ushort* hb_   = (ushort*)(ws + 40 * MB);
    ushort* wb    = (ushort*)(ws + 64 * MB);

    ushort* cnn_wb = wb;                    // 131072
    ushort* Wob    = wb + 131072;           // 262144
    ushort* wqkv   = wb + 393216;           // 786432 = [L][768][256]
    ushort* mw1b   = wb + 1179648;          // 786432
    ushort* mw2b   = wb + 1966080;          // 786432
    ushort* ow1b   = wb + 2752512;          // 131072
    ushort* ow2b   = wb + 2883584;          // 262144
    float*  bqkv   = (float*)(ws + 64 * MB + 6291456);   // [L][768] fp32

    // all conversions in one dispatch
    setup_kernel<<<dim3(5644), dim3(256), 0, stream>>>(
        cnn, cnn_w, Wo, Wq, Wk, Wv, mw1, mw2, ow1, ow2, bq, bk, bv,
        cnnb, wb, bqkv);

    // x = cnn @ cnn_w^T + cnn_b + tok[0]  -> x fp32 + xb bf16
    gemm_bt2_kernel<0, 0, true, true><<<dim3(M / 128, E_SZ / 64), dim3(256), 0, stream>>>(
        cnnb, cnn_wb, cnn_b, tok, x, xb, nullptr, M, C_SZ, E_SZ);

    for (int i = 0; i < L_SZ; ++i) {
        // fused QKV: q|k -> qkb [N][512], v -> vt transposed [b][h][32][512]
        gemm_bt2_kernel<0, 1, false, false><<<dim3(M / 128, HID / 64), dim3(256), 0, stream>>>(
            xb, wqkv + (size_t)i * 196608, bqkv + (size_t)i * 768, nullptr,
            nullptr, qkb, vt, M, E_SZ, HID);

        attn_v9<<<dim3(B_SZ * H_SZ), dim3(1024), 0, stream>>>(qkb, vt, ab_);

        // x = LN(x + ab @ Wo^T + bo)  (fused GEMM+add+LN)
        gemm_ln_kernel<false><<<dim3(M / 64), dim3(512), 0, stream>>>(
            ab_, Wob + (size_t)i * 65536, bo + (size_t)i * E_SZ,
            x, xb, ln1w + (size_t)i * E_SZ, ln1b + (size_t)i * E_SZ,
            nullptr, nullptr, E_SZ);

        // h = gelu(xb @ mw1^T + mb1) -> hb_ [N,768]
        gemm_bt2_kernel<1, 0, false, true><<<dim3(M / 128, HID / 64), dim3(256), 0, stream>>>(
            xb, mw1b + (size_t)i * HID * E_SZ, mb1 + (size_t)i * HID, nullptr,
            nullptr, hb_, nullptr, M, E_SZ, HID);

        // x = LN(x + hb @ mw2^T + mb2); last layer also applies final LN
        if (i < L_SZ - 1) {
            gemm_ln_kernel<false><<<dim3(M / 64), dim3(512), 0, stream>>>(
                hb_, mw2b + (size_t)i * E_SZ * HID, mb2 + (size_t)i * E_SZ,
                x, xb, ln2w + (size_t)i * E_SZ, ln2b + (size_t)i * E_SZ,
                nullptr, nullptr, HID);
        } else {
            gemm_ln_kernel<true><<<dim3(M / 64), dim3(512), 0, stream>>>(
                hb_, mw2b + (size_t)i * E_SZ * HID, mb2 + (size_t)i * E_SZ,
                x, xb, ln2w + (size_t)i * E_SZ, ln2b + (size_t)i * E_SZ,
                lnfw, lnfb, HID);
        }
    }

    // h = gelu(xb @ ow1^T + ob1) -> hb_ [N,512]
    gemm_bt2_kernel<1, 0, false, true><<<dim3(M / 128, (2 * E_SZ) / 64), dim3(256), 0, stream>>>(
        xb, ow1b, ob1, nullptr, nullptr, hb_, nullptr, M, E_SZ, 2 * E_SZ);
    // out = relu(hb @ ow2^T + ob2) -> d_out fp32
    gemm_bt2_kernel<2, 0, true, false><<<dim3(M / 128, C_SZ / 64), dim3(256), 0, stream>>>(
        hb_, ow2b, ob2, nullptr, (float*)d_out, nullptr, nullptr, M, 2 * E_SZ, C_SZ);
}